// Round 1
// baseline (1486.555 us; speedup 1.0000x reference)
//
#include <hip/hip_runtime.h>
#include <hip/hip_bf16.h>

// Jamba sparse MoE: B=4,S=2048,H=1024,F=4096,E=8,TOPK=2  (T=8192 tokens)
// Sparse top-2 execution: router -> plan -> scatter -> fused gate/up GEMM -> down GEMM.
// All GEMMs: bf16 MFMA 16x16x32, 128x128 tiles, BK=32, m97-style 2-barrier K-loop.

#define T_TOKENS 8192
#define H_DIM    1024
#define F_DIM    4096
#define E_NUM    8
#define NSLOT_CAP 17408   // 16384 assignments + 8 experts * 128-row padding
#define MAX_TILES 136     // sum ceil(count_e/128) <= 128 + 8

typedef __attribute__((ext_vector_type(8))) __bf16 bf16x8;
typedef __attribute__((ext_vector_type(4))) float  floatx4;
typedef __attribute__((ext_vector_type(8))) unsigned short ushort8;

__device__ __forceinline__ unsigned short f2bf(float f) {
    unsigned int u = __builtin_bit_cast(unsigned int, f);
    u += 0x7fffu + ((u >> 16) & 1u);          // RNE (inputs finite, no NaN path)
    return (unsigned short)(u >> 16);
}

__device__ __forceinline__ void stage16(const void* g, void* l) {
    __builtin_amdgcn_global_load_lds(
        (const __attribute__((address_space(1))) void*)g,
        (__attribute__((address_space(3))) void*)l, 16, 0, 0);
}

// ---------------- router: fp32 logits, softmax, top-2 (no renormalize) -------
__global__ __launch_bounds__(256) void router_kernel(
    const float* __restrict__ x, const float* __restrict__ rw,
    int* __restrict__ topk_id, float* __restrict__ topk_w, int* __restrict__ counts)
{
    __shared__ float s_rw[E_NUM * H_DIM];     // 32 KB
    int tid = threadIdx.x;
    for (int i = tid; i < E_NUM * H_DIM; i += 256) s_rw[i] = rw[i];
    __syncthreads();
    int wave = tid >> 6, lane = tid & 63;
    int token = blockIdx.x * 4 + wave;
    const float* xr = x + (size_t)token * H_DIM;
    float acc[E_NUM];
#pragma unroll
    for (int e = 0; e < E_NUM; e++) acc[e] = 0.f;
    for (int k = lane; k < H_DIM; k += 64) {
        float xv = xr[k];
#pragma unroll
        for (int e = 0; e < E_NUM; e++) acc[e] += xv * s_rw[e * H_DIM + k];
    }
#pragma unroll
    for (int e = 0; e < E_NUM; e++) {
        float v = acc[e];
#pragma unroll
        for (int off = 32; off > 0; off >>= 1) v += __shfl_xor(v, off, 64);
        acc[e] = v;
    }
    if (lane == 0) {
        float mx = acc[0];
#pragma unroll
        for (int e = 1; e < E_NUM; e++) mx = fmaxf(mx, acc[e]);
        float p[E_NUM]; float sum = 0.f;
#pragma unroll
        for (int e = 0; e < E_NUM; e++) { p[e] = __expf(acc[e] - mx); sum += p[e]; }
        float inv = 1.f / sum;
        int i0 = 0; float v0 = p[0];
#pragma unroll
        for (int e = 1; e < E_NUM; e++) if (p[e] > v0) { v0 = p[e]; i0 = e; }
        int i1 = -1; float v1 = -1.f;
#pragma unroll
        for (int e = 0; e < E_NUM; e++) if (e != i0 && p[e] > v1) { v1 = p[e]; i1 = e; }
        topk_id[token * 2] = i0;     topk_w[token * 2] = v0 * inv;
        topk_id[token * 2 + 1] = i1; topk_w[token * 2 + 1] = v1 * inv;
        atomicAdd(&counts[i0], 1);   atomicAdd(&counts[i1], 1);
    }
}

// ---------------- plan: prefix offsets (padded to 128) + tile table ----------
__global__ void plan_kernel(const int* __restrict__ counts, int* __restrict__ offs,
                            int* __restrict__ tile_expert, int* __restrict__ tile_row)
{
    if (threadIdx.x == 0 && blockIdx.x == 0) {
        int off = 0, t = 0;
        for (int e = 0; e < E_NUM; e++) {
            offs[e] = off;
            int nt = (counts[e] + 127) >> 7;
            for (int i = 0; i < nt; i++) { tile_expert[t] = e; tile_row[t] = off + i * 128; t++; }
            off += nt * 128;
        }
        offs[E_NUM] = off;
        for (; t < MAX_TILES; t++) { tile_expert[t] = -1; tile_row[t] = 0; }
    }
}

// ---------------- scatter assignments into padded per-expert segments --------
__global__ __launch_bounds__(256) void scatter_kernel(
    const int* __restrict__ topk_id, const float* __restrict__ topk_w,
    const int* __restrict__ offs, int* __restrict__ fill,
    int* __restrict__ token_list, float* __restrict__ w_list)
{
    int i = blockIdx.x * 256 + threadIdx.x;   // assignment index in [0, 2T)
    if (i < T_TOKENS * 2) {
        int e = topk_id[i];
        int pos = atomicAdd(&fill[e], 1);
        int slot = offs[e] + pos;
        token_list[slot] = i >> 1;
        w_list[slot] = topk_w[i];
    }
}

// ---------------- x fp32 -> bf16 ---------------------------------------------
__global__ __launch_bounds__(256) void cvt_x_kernel(
    const float* __restrict__ x, unsigned short* __restrict__ xb)
{
    int i = (blockIdx.x * 256 + threadIdx.x) * 4;
    float4 v = *(const float4*)(x + i);
    ushort4 o;
    o.x = f2bf(v.x); o.y = f2bf(v.y); o.z = f2bf(v.z); o.w = f2bf(v.w);
    *(ushort4*)(xb + i) = o;
}

// ---------------- fused gate+up gather-GEMM + silu ---------------------------
// grid (F/128, MAX_TILES), block 256. C[slot, f] = silu(x@gw^T) * (x@uw^T)
__global__ __launch_bounds__(256, 2) void gateup_kernel(
    const unsigned short* __restrict__ xb, const float* __restrict__ gate_w,
    const float* __restrict__ up_w, const int* __restrict__ token_list,
    const int* __restrict__ tile_expert, const int* __restrict__ tile_row,
    unsigned short* __restrict__ hid)
{
    int e = tile_expert[blockIdx.y];
    if (e < 0) return;
    int m0 = tile_row[blockIdx.y];
    int n0 = blockIdx.x * 128;

    __shared__ unsigned short As[128 * 32];
    __shared__ unsigned short Bg[128 * 32];
    __shared__ unsigned short Bu[128 * 32];

    int tid = threadIdx.x;
    int wave = tid >> 6, lane = tid & 63;

    // A gather staging: 2x global_load_lds(16B) per thread per K-tile
    int arow0 = wave * 16 + (lane >> 2);
    int aseg  = lane & 3;
    int tok0 = token_list[m0 + arow0];
    int tok1 = token_list[m0 + 64 + arow0];
    const unsigned short* ap0 = xb + (size_t)tok0 * H_DIM + aseg * 8;
    const unsigned short* ap1 = xb + (size_t)tok1 * H_DIM + aseg * 8;
    unsigned short* al0 = As + wave * 512;          // HW adds lane*16 bytes
    unsigned short* al1 = As + 2048 + wave * 512;

    // B staging: 16 fp32 -> 16 bf16 per thread per matrix per K-tile
    int brow = tid >> 1, bhalf = tid & 1;
    const float* gp = gate_w + ((size_t)e * F_DIM + n0 + brow) * H_DIM + bhalf * 16;
    const float* upp = up_w  + ((size_t)e * F_DIM + n0 + brow) * H_DIM + bhalf * 16;
    int bofs = brow * 32 + bhalf * 16;

    int wm = (wave & 1) * 64, wn = (wave >> 1) * 64;
    int lrow = lane & 15, lquad = lane >> 4;

    floatx4 accg[4][4], accu[4][4];
#pragma unroll
    for (int i = 0; i < 4; i++)
#pragma unroll
        for (int j = 0; j < 4; j++) {
            accg[i][j] = (floatx4){0.f, 0.f, 0.f, 0.f};
            accu[i][j] = (floatx4){0.f, 0.f, 0.f, 0.f};
        }

    for (int kt = 0; kt < H_DIM / 32; kt++) {
        const float* gk = gp + kt * 32;
        const float* uk = upp + kt * 32;
        float4 g0 = *(const float4*)(gk);      float4 g1 = *(const float4*)(gk + 4);
        float4 g2 = *(const float4*)(gk + 8);  float4 g3 = *(const float4*)(gk + 12);
        float4 u0 = *(const float4*)(uk);      float4 u1 = *(const float4*)(uk + 4);
        float4 u2 = *(const float4*)(uk + 8);  float4 u3 = *(const float4*)(uk + 12);

        __syncthreads();   // previous iter done reading LDS

        stage16(ap0 + kt * 32, al0);
        stage16(ap1 + kt * 32, al1);

        ushort8 p0, p1, q0, q1;
        p0[0]=f2bf(g0.x); p0[1]=f2bf(g0.y); p0[2]=f2bf(g0.z); p0[3]=f2bf(g0.w);
        p0[4]=f2bf(g1.x); p0[5]=f2bf(g1.y); p0[6]=f2bf(g1.z); p0[7]=f2bf(g1.w);
        p1[0]=f2bf(g2.x); p1[1]=f2bf(g2.y); p1[2]=f2bf(g2.z); p1[3]=f2bf(g2.w);
        p1[4]=f2bf(g3.x); p1[5]=f2bf(g3.y); p1[6]=f2bf(g3.z); p1[7]=f2bf(g3.w);
        q0[0]=f2bf(u0.x); q0[1]=f2bf(u0.y); q0[2]=f2bf(u0.z); q0[3]=f2bf(u0.w);
        q0[4]=f2bf(u1.x); q0[5]=f2bf(u1.y); q0[6]=f2bf(u1.z); q0[7]=f2bf(u1.w);
        q1[0]=f2bf(u2.x); q1[1]=f2bf(u2.y); q1[2]=f2bf(u2.z); q1[3]=f2bf(u2.w);
        q1[4]=f2bf(u3.x); q1[5]=f2bf(u3.y); q1[6]=f2bf(u3.z); q1[7]=f2bf(u3.w);
        *(ushort8*)(&Bg[bofs]) = p0;  *(ushort8*)(&Bg[bofs + 8]) = p1;
        *(ushort8*)(&Bu[bofs]) = q0;  *(ushort8*)(&Bu[bofs + 8]) = q1;

        __syncthreads();   // staging visible (drains vmcnt+lgkm)

        bf16x8 af[4], bgf[4], buf2[4];
#pragma unroll
        for (int mi = 0; mi < 4; mi++)
            af[mi] = *(const bf16x8*)(&As[(wm + mi * 16 + lrow) * 32 + lquad * 8]);
#pragma unroll
        for (int ni = 0; ni < 4; ni++) {
            bgf[ni]  = *(const bf16x8*)(&Bg[(wn + ni * 16 + lrow) * 32 + lquad * 8]);
            buf2[ni] = *(const bf16x8*)(&Bu[(wn + ni * 16 + lrow) * 32 + lquad * 8]);
        }
#pragma unroll
        for (int mi = 0; mi < 4; mi++)
#pragma unroll
            for (int ni = 0; ni < 4; ni++) {
                accg[mi][ni] = __builtin_amdgcn_mfma_f32_16x16x32_bf16(af[mi], bgf[ni],  accg[mi][ni], 0, 0, 0);
                accu[mi][ni] = __builtin_amdgcn_mfma_f32_16x16x32_bf16(af[mi], buf2[ni], accu[mi][ni], 0, 0, 0);
            }
    }

    // epilogue: hid = silu(g)*u -> bf16   (C/D: col=lane&15, row=quad*4+reg)
#pragma unroll
    for (int mi = 0; mi < 4; mi++)
#pragma unroll
        for (int r = 0; r < 4; r++) {
            size_t srow = (size_t)(m0 + wm + mi * 16 + lquad * 4 + r);
            unsigned short* hrow = hid + srow * F_DIM + n0 + wn + lrow;
#pragma unroll
            for (int ni = 0; ni < 4; ni++) {
                float g = accg[mi][ni][r];
                float u = accu[mi][ni][r];
                float sg = __builtin_amdgcn_rcpf(1.f + __expf(-g));
                hrow[ni * 16] = f2bf(g * sg * u);
            }
        }
}

// ---------------- down GEMM + weighted atomic scatter-add --------------------
// grid (H/128, MAX_TILES). out[tok,h] += w_slot * sum_f hid[slot,f]*dw[h,f]
__global__ __launch_bounds__(256, 2) void down_kernel(
    const unsigned short* __restrict__ hid, const float* __restrict__ down_w,
    const int* __restrict__ token_list, const float* __restrict__ w_list,
    const int* __restrict__ tile_expert, const int* __restrict__ tile_row,
    float* __restrict__ out)
{
    int e = tile_expert[blockIdx.y];
    if (e < 0) return;
    int m0 = tile_row[blockIdx.y];
    int n0 = blockIdx.x * 128;

    __shared__ unsigned short As[128 * 32];
    __shared__ unsigned short Bs[128 * 32];

    int tid = threadIdx.x;
    int wave = tid >> 6, lane = tid & 63;

    int arow0 = wave * 16 + (lane >> 2);
    int aseg  = lane & 3;
    const unsigned short* ap0 = hid + (size_t)(m0 + arow0) * F_DIM + aseg * 8;
    const unsigned short* ap1 = hid + (size_t)(m0 + 64 + arow0) * F_DIM + aseg * 8;
    unsigned short* al0 = As + wave * 512;
    unsigned short* al1 = As + 2048 + wave * 512;

    int brow = tid >> 1, bhalf = tid & 1;
    const float* bp = down_w + ((size_t)e * H_DIM + n0 + brow) * F_DIM + bhalf * 16;
    int bofs = brow * 32 + bhalf * 16;

    int wm = (wave & 1) * 64, wn = (wave >> 1) * 64;
    int lrow = lane & 15, lquad = lane >> 4;

    floatx4 acc[4][4];
#pragma unroll
    for (int i = 0; i < 4; i++)
#pragma unroll
        for (int j = 0; j < 4; j++) acc[i][j] = (floatx4){0.f, 0.f, 0.f, 0.f};

    for (int kt = 0; kt < F_DIM / 32; kt++) {
        const float* bk = bp + kt * 32;
        float4 b0 = *(const float4*)(bk);      float4 b1 = *(const float4*)(bk + 4);
        float4 b2 = *(const float4*)(bk + 8);  float4 b3 = *(const float4*)(bk + 12);

        __syncthreads();

        stage16(ap0 + kt * 32, al0);
        stage16(ap1 + kt * 32, al1);

        ushort8 p0, p1;
        p0[0]=f2bf(b0.x); p0[1]=f2bf(b0.y); p0[2]=f2bf(b0.z); p0[3]=f2bf(b0.w);
        p0[4]=f2bf(b1.x); p0[5]=f2bf(b1.y); p0[6]=f2bf(b1.z); p0[7]=f2bf(b1.w);
        p1[0]=f2bf(b2.x); p1[1]=f2bf(b2.y); p1[2]=f2bf(b2.z); p1[3]=f2bf(b2.w);
        p1[4]=f2bf(b3.x); p1[5]=f2bf(b3.y); p1[6]=f2bf(b3.z); p1[7]=f2bf(b3.w);
        *(ushort8*)(&Bs[bofs]) = p0;  *(ushort8*)(&Bs[bofs + 8]) = p1;

        __syncthreads();

        bf16x8 af[4], bf[4];
#pragma unroll
        for (int mi = 0; mi < 4; mi++)
            af[mi] = *(const bf16x8*)(&As[(wm + mi * 16 + lrow) * 32 + lquad * 8]);
#pragma unroll
        for (int ni = 0; ni < 4; ni++)
            bf[ni] = *(const bf16x8*)(&Bs[(wn + ni * 16 + lrow) * 32 + lquad * 8]);
#pragma unroll
        for (int mi = 0; mi < 4; mi++)
#pragma unroll
            for (int ni = 0; ni < 4; ni++)
                acc[mi][ni] = __builtin_amdgcn_mfma_f32_16x16x32_bf16(af[mi], bf[ni], acc[mi][ni], 0, 0, 0);
    }

#pragma unroll
    for (int mi = 0; mi < 4; mi++)
#pragma unroll
        for (int r = 0; r < 4; r++) {
            int slot = m0 + wm + mi * 16 + lquad * 4 + r;
            int tok = token_list[slot];
            float w = w_list[slot];                 // 0 for padded slots
            float* orow = out + (size_t)tok * H_DIM + n0 + wn + lrow;
#pragma unroll
            for (int ni = 0; ni < 4; ni++)
                atomicAdd(&orow[ni * 16], w * acc[mi][ni][r]);
        }
}

// ---------------- launch -----------------------------------------------------
extern "C" void kernel_launch(void* const* d_in, const int* in_sizes, int n_in,
                              void* d_out, int out_size, void* d_ws, size_t ws_size,
                              hipStream_t stream) {
    (void)in_sizes; (void)n_in;
    const float* x        = (const float*)d_in[0];
    const float* router_w = (const float*)d_in[1];
    const float* gate_w   = (const float*)d_in[2];
    const float* up_w     = (const float*)d_in[3];
    const float* down_w   = (const float*)d_in[4];
    float* out = (float*)d_out;

    char* ws = (char*)d_ws;
    size_t off = 0;
    unsigned short* xb  = (unsigned short*)(ws + off); off += (size_t)T_TOKENS * H_DIM * 2;   // 16 MB
    unsigned short* hid = (unsigned short*)(ws + off); off += (size_t)NSLOT_CAP * F_DIM * 2;  // 136 MB
    int*   topk_id = (int*)(ws + off);   off += T_TOKENS * 2 * 4;
    float* topk_w  = (float*)(ws + off); off += T_TOKENS * 2 * 4;
    char* zbase = ws + off;                                // zero-init region starts here
    int*   token_list = (int*)(ws + off);   off += NSLOT_CAP * 4;
    float* w_list     = (float*)(ws + off); off += NSLOT_CAP * 4;
    int* counts = (int*)(ws + off); off += 32;
    int* offs   = (int*)(ws + off); off += 64;
    int* fill   = (int*)(ws + off); off += 32;
    int* tile_expert = (int*)(ws + off); off += 576;
    int* tile_row    = (int*)(ws + off); off += 576;
    if (off > ws_size) return;   // workspace too small — fail loudly via mismatch

    hipMemsetAsync(zbase, 0, (size_t)((ws + off) - zbase), stream);
    hipMemsetAsync(d_out, 0, (size_t)out_size * 4, stream);

    cvt_x_kernel  <<<(T_TOKENS * H_DIM / 4) / 256, 256, 0, stream>>>(x, xb);
    router_kernel <<<T_TOKENS / 4, 256, 0, stream>>>(x, router_w, topk_id, topk_w, counts);
    plan_kernel   <<<1, 1, 0, stream>>>(counts, offs, tile_expert, tile_row);
    scatter_kernel<<<(T_TOKENS * 2) / 256, 256, 0, stream>>>(topk_id, topk_w, offs, fill, token_list, w_list);
    gateup_kernel <<<dim3(F_DIM / 128, MAX_TILES), 256, 0, stream>>>(
        xb, gate_w, up_w, token_list, tile_expert, tile_row, hid);
    down_kernel   <<<dim3(H_DIM / 128, MAX_TILES), 256, 0, stream>>>(
        hid, down_w, token_list, w_list, tile_expert, tile_row, out);
}

// Round 2
// 1295.612 us; speedup vs baseline: 1.1474x; 1.1474x over previous
//
#include <hip/hip_runtime.h>
#include <hip/hip_bf16.h>

// Jamba sparse MoE: B=4,S=2048,H=1024,F=4096,E=8,TOPK=2  (T=8192 tokens)
// Round 2: pre-convert weights to bf16 (if ws allows), pure global_load_lds
// staging for A and B, XOR-swizzled LDS segments (2-way = free), 128x64 gateup
// tile (64 acc regs -> 4 blocks/CU). Fallback to round-1 kernels if ws small.

#define T_TOKENS 8192
#define H_DIM    1024
#define F_DIM    4096
#define E_NUM    8
#define NSLOT_CAP 17408   // 16384 assignments + 8 experts * 128-row padding
#define MAX_TILES 136     // sum ceil(count_e/128) <= 128 + 8

typedef __attribute__((ext_vector_type(8))) __bf16 bf16x8;
typedef __attribute__((ext_vector_type(4))) float  floatx4;
typedef __attribute__((ext_vector_type(8))) unsigned short ushort8;

__device__ __forceinline__ unsigned short f2bf(float f) {
    unsigned int u = __builtin_bit_cast(unsigned int, f);
    u += 0x7fffu + ((u >> 16) & 1u);          // RNE (inputs finite)
    return (unsigned short)(u >> 16);
}

__device__ __forceinline__ void stage16(const void* g, void* l) {
    __builtin_amdgcn_global_load_lds(
        (const __attribute__((address_space(1))) void*)g,
        (__attribute__((address_space(3))) void*)l, 16, 0, 0);
}

// ---------------- router: fp32 logits, softmax, top-2 (no renormalize) -------
__global__ __launch_bounds__(256) void router_kernel(
    const float* __restrict__ x, const float* __restrict__ rw,
    int* __restrict__ topk_id, float* __restrict__ topk_w, int* __restrict__ counts)
{
    __shared__ float s_rw[E_NUM * H_DIM];     // 32 KB
    int tid = threadIdx.x;
    for (int i = tid; i < E_NUM * H_DIM; i += 256) s_rw[i] = rw[i];
    __syncthreads();
    int wave = tid >> 6, lane = tid & 63;
    int token = blockIdx.x * 4 + wave;
    const float* xr = x + (size_t)token * H_DIM;
    float acc[E_NUM];
#pragma unroll
    for (int e = 0; e < E_NUM; e++) acc[e] = 0.f;
    for (int k = lane; k < H_DIM; k += 64) {
        float xv = xr[k];
#pragma unroll
        for (int e = 0; e < E_NUM; e++) acc[e] += xv * s_rw[e * H_DIM + k];
    }
#pragma unroll
    for (int e = 0; e < E_NUM; e++) {
        float v = acc[e];
#pragma unroll
        for (int off = 32; off > 0; off >>= 1) v += __shfl_xor(v, off, 64);
        acc[e] = v;
    }
    if (lane == 0) {
        float mx = acc[0];
#pragma unroll
        for (int e = 1; e < E_NUM; e++) mx = fmaxf(mx, acc[e]);
        float p[E_NUM]; float sum = 0.f;
#pragma unroll
        for (int e = 0; e < E_NUM; e++) { p[e] = __expf(acc[e] - mx); sum += p[e]; }
        float inv = 1.f / sum;
        int i0 = 0; float v0 = p[0];
#pragma unroll
        for (int e = 1; e < E_NUM; e++) if (p[e] > v0) { v0 = p[e]; i0 = e; }
        int i1 = -1; float v1 = -1.f;
#pragma unroll
        for (int e = 0; e < E_NUM; e++) if (e != i0 && p[e] > v1) { v1 = p[e]; i1 = e; }
        topk_id[token * 2] = i0;     topk_w[token * 2] = v0 * inv;
        topk_id[token * 2 + 1] = i1; topk_w[token * 2 + 1] = v1 * inv;
        atomicAdd(&counts[i0], 1);   atomicAdd(&counts[i1], 1);
    }
}

// ---------------- plan: prefix offsets (padded to 128) + tile table ----------
__global__ void plan_kernel(const int* __restrict__ counts, int* __restrict__ offs,
                            int* __restrict__ tile_expert, int* __restrict__ tile_row)
{
    if (threadIdx.x == 0 && blockIdx.x == 0) {
        int off = 0, t = 0;
        for (int e = 0; e < E_NUM; e++) {
            offs[e] = off;
            int nt = (counts[e] + 127) >> 7;
            for (int i = 0; i < nt; i++) { tile_expert[t] = e; tile_row[t] = off + i * 128; t++; }
            off += nt * 128;
        }
        offs[E_NUM] = off;
        for (; t < MAX_TILES; t++) { tile_expert[t] = -1; tile_row[t] = 0; }
    }
}

// ---------------- scatter assignments into padded per-expert segments --------
__global__ __launch_bounds__(256) void scatter_kernel(
    const int* __restrict__ topk_id, const float* __restrict__ topk_w,
    const int* __restrict__ offs, int* __restrict__ fill,
    int* __restrict__ token_list, float* __restrict__ w_list)
{
    int i = blockIdx.x * 256 + threadIdx.x;   // assignment index in [0, 2T)
    if (i < T_TOKENS * 2) {
        int e = topk_id[i];
        int pos = atomicAdd(&fill[e], 1);
        int slot = offs[e] + pos;
        token_list[slot] = i >> 1;
        w_list[slot] = topk_w[i];
    }
}

// ---------------- fp32 -> bf16 converters ------------------------------------
__global__ __launch_bounds__(256) void cvt_x_kernel(
    const float* __restrict__ x, unsigned short* __restrict__ xb)
{
    int i = (blockIdx.x * 256 + threadIdx.x) * 4;
    float4 v = *(const float4*)(x + i);
    ushort4 o;
    o.x = f2bf(v.x); o.y = f2bf(v.y); o.z = f2bf(v.z); o.w = f2bf(v.w);
    *(ushort4*)(xb + i) = o;
}

__global__ __launch_bounds__(256) void cvt_w_kernel(
    const float* __restrict__ src, unsigned short* __restrict__ dst)
{
    size_t i = ((size_t)blockIdx.x * 256 + threadIdx.x) * 4;
    float4 v = *(const float4*)(src + i);
    ushort4 o;
    o.x = f2bf(v.x); o.y = f2bf(v.y); o.z = f2bf(v.z); o.w = f2bf(v.w);
    *(ushort4*)(dst + i) = o;
}

// ============================================================================
// NEW PATH: bf16 weights, pure global_load_lds staging, swizzled LDS.
// LDS segment swizzle: a tile row is 32 bf16 = four 16B segments; data segment
// s of row r is stored at physical segment s ^ ((r>>1)&3). Staging lane
// (phys = lane&3, row-in-16 = lane>>2) fetches global seg (lane&3)^((lane>>3)&3).
// Frag reads use phys = lquad ^ ((lrow>>1)&3)  => 2-way banks (free).
// ============================================================================

// -------- gateup: 128M x 64N tile, dual gate+up, grid (F/64, MAX_TILES) ------
__global__ __launch_bounds__(256, 4) void gateup_bf16_kernel(
    const unsigned short* __restrict__ xb, const unsigned short* __restrict__ gwb,
    const unsigned short* __restrict__ uwb, const int* __restrict__ token_list,
    const int* __restrict__ tile_expert, const int* __restrict__ tile_row,
    unsigned short* __restrict__ hid)
{
    int e = tile_expert[blockIdx.y];
    if (e < 0) return;
    int m0 = tile_row[blockIdx.y];
    int n0 = blockIdx.x * 64;

    __shared__ unsigned short As[128 * 32];   // 8 KB
    __shared__ unsigned short Bg[64 * 32];    // 4 KB
    __shared__ unsigned short Bu[64 * 32];    // 4 KB

    int tid = threadIdx.x;
    int wave = tid >> 6, lane = tid & 63;
    int r16 = lane >> 2;
    int seg = (lane & 3) ^ ((lane >> 3) & 3);   // data segment this lane fetches

    // A: rows wave*16 + {0,64}
    int tok0 = token_list[m0 + wave * 16 + r16];
    int tok1 = token_list[m0 + 64 + wave * 16 + r16];
    const unsigned short* ap0 = xb + (size_t)tok0 * H_DIM + seg * 8;
    const unsigned short* ap1 = xb + (size_t)tok1 * H_DIM + seg * 8;
    unsigned short* al0 = As + wave * 512;           // HW adds lane*16B
    unsigned short* al1 = As + 2048 + wave * 512;

    // B: 64 rows, one 16-row block per wave per matrix
    size_t brow = (size_t)e * F_DIM + n0 + wave * 16 + r16;
    const unsigned short* gp = gwb + brow * H_DIM + seg * 8;
    const unsigned short* up = uwb + brow * H_DIM + seg * 8;
    unsigned short* bgl = Bg + wave * 512;
    unsigned short* bul = Bu + wave * 512;

    int wm = (wave & 1) * 64, wn = (wave >> 1) * 32;
    int lrow = lane & 15, lquad = lane >> 4;
    int pq = (lquad ^ ((lrow >> 1) & 3)) * 8;        // swizzled read column

    floatx4 accg[4][2], accu[4][2];
#pragma unroll
    for (int i = 0; i < 4; i++)
#pragma unroll
        for (int j = 0; j < 2; j++) {
            accg[i][j] = (floatx4){0.f, 0.f, 0.f, 0.f};
            accu[i][j] = (floatx4){0.f, 0.f, 0.f, 0.f};
        }

    for (int kt = 0; kt < H_DIM / 32; kt++) {
        int ko = kt * 32;
        __syncthreads();                 // prev iter done reading LDS
        stage16(ap0 + ko, al0);
        stage16(ap1 + ko, al1);
        stage16(gp + ko, bgl);
        stage16(up + ko, bul);
        __syncthreads();                 // staging visible

        bf16x8 af[4], bgf[2], buf2[2];
#pragma unroll
        for (int mi = 0; mi < 4; mi++)
            af[mi] = *(const bf16x8*)(&As[(wm + mi * 16 + lrow) * 32 + pq]);
#pragma unroll
        for (int ni = 0; ni < 2; ni++) {
            bgf[ni]  = *(const bf16x8*)(&Bg[(wn + ni * 16 + lrow) * 32 + pq]);
            buf2[ni] = *(const bf16x8*)(&Bu[(wn + ni * 16 + lrow) * 32 + pq]);
        }
#pragma unroll
        for (int mi = 0; mi < 4; mi++)
#pragma unroll
            for (int ni = 0; ni < 2; ni++) {
                accg[mi][ni] = __builtin_amdgcn_mfma_f32_16x16x32_bf16(af[mi], bgf[ni],  accg[mi][ni], 0, 0, 0);
                accu[mi][ni] = __builtin_amdgcn_mfma_f32_16x16x32_bf16(af[mi], buf2[ni], accu[mi][ni], 0, 0, 0);
            }
    }

    // epilogue: hid = silu(g)*u -> bf16   (C/D: col=lane&15, row=quad*4+reg)
#pragma unroll
    for (int mi = 0; mi < 4; mi++)
#pragma unroll
        for (int r = 0; r < 4; r++) {
            size_t srow = (size_t)(m0 + wm + mi * 16 + lquad * 4 + r);
            unsigned short* hrow = hid + srow * F_DIM + n0 + wn + lrow;
#pragma unroll
            for (int ni = 0; ni < 2; ni++) {
                float g = accg[mi][ni][r];
                float u = accu[mi][ni][r];
                float sg = __builtin_amdgcn_rcpf(1.f + __expf(-g));
                hrow[ni * 16] = f2bf(g * sg * u);
            }
        }
}

// -------- down: 128M x 128N tile, grid (H/128, MAX_TILES) --------------------
__global__ __launch_bounds__(256, 3) void down_bf16_kernel(
    const unsigned short* __restrict__ hid, const unsigned short* __restrict__ dwb,
    const int* __restrict__ token_list, const float* __restrict__ w_list,
    const int* __restrict__ tile_expert, const int* __restrict__ tile_row,
    float* __restrict__ out)
{
    int e = tile_expert[blockIdx.y];
    if (e < 0) return;
    int m0 = tile_row[blockIdx.y];
    int n0 = blockIdx.x * 128;

    __shared__ unsigned short As[128 * 32];
    __shared__ unsigned short Bs[128 * 32];

    int tid = threadIdx.x;
    int wave = tid >> 6, lane = tid & 63;
    int r16 = lane >> 2;
    int seg = (lane & 3) ^ ((lane >> 3) & 3);

    const unsigned short* ap0 = hid + (size_t)(m0 + wave * 16 + r16) * F_DIM + seg * 8;
    const unsigned short* ap1 = hid + (size_t)(m0 + 64 + wave * 16 + r16) * F_DIM + seg * 8;
    unsigned short* al0 = As + wave * 512;
    unsigned short* al1 = As + 2048 + wave * 512;

    size_t brow = (size_t)e * H_DIM + n0 + wave * 16 + r16;
    const unsigned short* bp0 = dwb + brow * F_DIM + seg * 8;
    const unsigned short* bp1 = dwb + (brow + 64) * F_DIM + seg * 8;
    unsigned short* bl0 = Bs + wave * 512;
    unsigned short* bl1 = Bs + 2048 + wave * 512;

    int wm = (wave & 1) * 64, wn = (wave >> 1) * 64;
    int lrow = lane & 15, lquad = lane >> 4;
    int pq = (lquad ^ ((lrow >> 1) & 3)) * 8;

    floatx4 acc[4][4];
#pragma unroll
    for (int i = 0; i < 4; i++)
#pragma unroll
        for (int j = 0; j < 4; j++) acc[i][j] = (floatx4){0.f, 0.f, 0.f, 0.f};

    for (int kt = 0; kt < F_DIM / 32; kt++) {
        int ko = kt * 32;
        __syncthreads();
        stage16(ap0 + ko, al0);
        stage16(ap1 + ko, al1);
        stage16(bp0 + ko, bl0);
        stage16(bp1 + ko, bl1);
        __syncthreads();

        bf16x8 af[4], bf[4];
#pragma unroll
        for (int mi = 0; mi < 4; mi++)
            af[mi] = *(const bf16x8*)(&As[(wm + mi * 16 + lrow) * 32 + pq]);
#pragma unroll
        for (int ni = 0; ni < 4; ni++)
            bf[ni] = *(const bf16x8*)(&Bs[(wn + ni * 16 + lrow) * 32 + pq]);
#pragma unroll
        for (int mi = 0; mi < 4; mi++)
#pragma unroll
            for (int ni = 0; ni < 4; ni++)
                acc[mi][ni] = __builtin_amdgcn_mfma_f32_16x16x32_bf16(af[mi], bf[ni], acc[mi][ni], 0, 0, 0);
    }

#pragma unroll
    for (int mi = 0; mi < 4; mi++)
#pragma unroll
        for (int r = 0; r < 4; r++) {
            int slot = m0 + wm + mi * 16 + lquad * 4 + r;
            int tok = token_list[slot];
            float w = w_list[slot];                 // 0 for padded slots
            float* orow = out + (size_t)tok * H_DIM + n0 + wn + lrow;
#pragma unroll
            for (int ni = 0; ni < 4; ni++)
                atomicAdd(&orow[ni * 16], w * acc[mi][ni][r]);
        }
}

// ============================================================================
// FALLBACK PATH (round-1 kernels, fp32 weights converted in-loop)
// ============================================================================
__global__ __launch_bounds__(256, 2) void gateup_kernel(
    const unsigned short* __restrict__ xb, const float* __restrict__ gate_w,
    const float* __restrict__ up_w, const int* __restrict__ token_list,
    const int* __restrict__ tile_expert, const int* __restrict__ tile_row,
    unsigned short* __restrict__ hid)
{
    int e = tile_expert[blockIdx.y];
    if (e < 0) return;
    int m0 = tile_row[blockIdx.y];
    int n0 = blockIdx.x * 128;

    __shared__ unsigned short As[128 * 32];
    __shared__ unsigned short Bg[128 * 32];
    __shared__ unsigned short Bu[128 * 32];

    int tid = threadIdx.x;
    int wave = tid >> 6, lane = tid & 63;

    int arow0 = wave * 16 + (lane >> 2);
    int aseg  = lane & 3;
    int tok0 = token_list[m0 + arow0];
    int tok1 = token_list[m0 + 64 + arow0];
    const unsigned short* ap0 = xb + (size_t)tok0 * H_DIM + aseg * 8;
    const unsigned short* ap1 = xb + (size_t)tok1 * H_DIM + aseg * 8;
    unsigned short* al0 = As + wave * 512;
    unsigned short* al1 = As + 2048 + wave * 512;

    int brow = tid >> 1, bhalf = tid & 1;
    const float* gp = gate_w + ((size_t)e * F_DIM + n0 + brow) * H_DIM + bhalf * 16;
    const float* upp = up_w  + ((size_t)e * F_DIM + n0 + brow) * H_DIM + bhalf * 16;
    int bofs = brow * 32 + bhalf * 16;

    int wm = (wave & 1) * 64, wn = (wave >> 1) * 64;
    int lrow = lane & 15, lquad = lane >> 4;

    floatx4 accg[4][4], accu[4][4];
#pragma unroll
    for (int i = 0; i < 4; i++)
#pragma unroll
        for (int j = 0; j < 4; j++) {
            accg[i][j] = (floatx4){0.f, 0.f, 0.f, 0.f};
            accu[i][j] = (floatx4){0.f, 0.f, 0.f, 0.f};
        }

    for (int kt = 0; kt < H_DIM / 32; kt++) {
        const float* gk = gp + kt * 32;
        const float* uk = upp + kt * 32;
        float4 g0 = *(const float4*)(gk);      float4 g1 = *(const float4*)(gk + 4);
        float4 g2 = *(const float4*)(gk + 8);  float4 g3 = *(const float4*)(gk + 12);
        float4 u0 = *(const float4*)(uk);      float4 u1 = *(const float4*)(uk + 4);
        float4 u2 = *(const float4*)(uk + 8);  float4 u3 = *(const float4*)(uk + 12);

        __syncthreads();
        stage16(ap0 + kt * 32, al0);
        stage16(ap1 + kt * 32, al1);

        ushort8 p0, p1, q0, q1;
        p0[0]=f2bf(g0.x); p0[1]=f2bf(g0.y); p0[2]=f2bf(g0.z); p0[3]=f2bf(g0.w);
        p0[4]=f2bf(g1.x); p0[5]=f2bf(g1.y); p0[6]=f2bf(g1.z); p0[7]=f2bf(g1.w);
        p1[0]=f2bf(g2.x); p1[1]=f2bf(g2.y); p1[2]=f2bf(g2.z); p1[3]=f2bf(g2.w);
        p1[4]=f2bf(g3.x); p1[5]=f2bf(g3.y); p1[6]=f2bf(g3.z); p1[7]=f2bf(g3.w);
        q0[0]=f2bf(u0.x); q0[1]=f2bf(u0.y); q0[2]=f2bf(u0.z); q0[3]=f2bf(u0.w);
        q0[4]=f2bf(u1.x); q0[5]=f2bf(u1.y); q0[6]=f2bf(u1.z); q0[7]=f2bf(u1.w);
        q1[0]=f2bf(u2.x); q1[1]=f2bf(u2.y); q1[2]=f2bf(u2.z); q1[3]=f2bf(u2.w);
        q1[4]=f2bf(u3.x); q1[5]=f2bf(u3.y); q1[6]=f2bf(u3.z); q1[7]=f2bf(u3.w);
        *(ushort8*)(&Bg[bofs]) = p0;  *(ushort8*)(&Bg[bofs + 8]) = p1;
        *(ushort8*)(&Bu[bofs]) = q0;  *(ushort8*)(&Bu[bofs + 8]) = q1;

        __syncthreads();

        bf16x8 af[4], bgf[4], buf2[4];
#pragma unroll
        for (int mi = 0; mi < 4; mi++)
            af[mi] = *(const bf16x8*)(&As[(wm + mi * 16 + lrow) * 32 + lquad * 8]);
#pragma unroll
        for (int ni = 0; ni < 4; ni++) {
            bgf[ni]  = *(const bf16x8*)(&Bg[(wn + ni * 16 + lrow) * 32 + lquad * 8]);
            buf2[ni] = *(const bf16x8*)(&Bu[(wn + ni * 16 + lrow) * 32 + lquad * 8]);
        }
#pragma unroll
        for (int mi = 0; mi < 4; mi++)
#pragma unroll
            for (int ni = 0; ni < 4; ni++) {
                accg[mi][ni] = __builtin_amdgcn_mfma_f32_16x16x32_bf16(af[mi], bgf[ni],  accg[mi][ni], 0, 0, 0);
                accu[mi][ni] = __builtin_amdgcn_mfma_f32_16x16x32_bf16(af[mi], buf2[ni], accu[mi][ni], 0, 0, 0);
            }
    }

#pragma unroll
    for (int mi = 0; mi < 4; mi++)
#pragma unroll
        for (int r = 0; r < 4; r++) {
            size_t srow = (size_t)(m0 + wm + mi * 16 + lquad * 4 + r);
            unsigned short* hrow = hid + srow * F_DIM + n0 + wn + lrow;
#pragma unroll
            for (int ni = 0; ni < 4; ni++) {
                float g = accg[mi][ni][r];
                float u = accu[mi][ni][r];
                float sg = __builtin_amdgcn_rcpf(1.f + __expf(-g));
                hrow[ni * 16] = f2bf(g * sg * u);
            }
        }
}

__global__ __launch_bounds__(256, 2) void down_kernel(
    const unsigned short* __restrict__ hid, const float* __restrict__ down_w,
    const int* __restrict__ token_list, const float* __restrict__ w_list,
    const int* __restrict__ tile_expert, const int* __restrict__ tile_row,
    float* __restrict__ out)
{
    int e = tile_expert[blockIdx.y];
    if (e < 0) return;
    int m0 = tile_row[blockIdx.y];
    int n0 = blockIdx.x * 128;

    __shared__ unsigned short As[128 * 32];
    __shared__ unsigned short Bs[128 * 32];

    int tid = threadIdx.x;
    int wave = tid >> 6, lane = tid & 63;

    int arow0 = wave * 16 + (lane >> 2);
    int aseg  = lane & 3;
    const unsigned short* ap0 = hid + (size_t)(m0 + arow0) * F_DIM + aseg * 8;
    const unsigned short* ap1 = hid + (size_t)(m0 + 64 + arow0) * F_DIM + aseg * 8;
    unsigned short* al0 = As + wave * 512;
    unsigned short* al1 = As + 2048 + wave * 512;

    int brow = tid >> 1, bhalf = tid & 1;
    const float* bp = down_w + ((size_t)e * H_DIM + n0 + brow) * F_DIM + bhalf * 16;
    int bofs = brow * 32 + bhalf * 16;

    int wm = (wave & 1) * 64, wn = (wave >> 1) * 64;
    int lrow = lane & 15, lquad = lane >> 4;

    floatx4 acc[4][4];
#pragma unroll
    for (int i = 0; i < 4; i++)
#pragma unroll
        for (int j = 0; j < 4; j++) acc[i][j] = (floatx4){0.f, 0.f, 0.f, 0.f};

    for (int kt = 0; kt < F_DIM / 32; kt++) {
        const float* bk = bp + kt * 32;
        float4 b0 = *(const float4*)(bk);      float4 b1 = *(const float4*)(bk + 4);
        float4 b2 = *(const float4*)(bk + 8);  float4 b3 = *(const float4*)(bk + 12);

        __syncthreads();
        stage16(ap0 + kt * 32, al0);
        stage16(ap1 + kt * 32, al1);

        ushort8 p0, p1;
        p0[0]=f2bf(b0.x); p0[1]=f2bf(b0.y); p0[2]=f2bf(b0.z); p0[3]=f2bf(b0.w);
        p0[4]=f2bf(b1.x); p0[5]=f2bf(b1.y); p0[6]=f2bf(b1.z); p0[7]=f2bf(b1.w);
        p1[0]=f2bf(b2.x); p1[1]=f2bf(b2.y); p1[2]=f2bf(b2.z); p1[3]=f2bf(b2.w);
        p1[4]=f2bf(b3.x); p1[5]=f2bf(b3.y); p1[6]=f2bf(b3.z); p1[7]=f2bf(b3.w);
        *(ushort8*)(&Bs[bofs]) = p0;  *(ushort8*)(&Bs[bofs + 8]) = p1;

        __syncthreads();

        bf16x8 af[4], bf[4];
#pragma unroll
        for (int mi = 0; mi < 4; mi++)
            af[mi] = *(const bf16x8*)(&As[(wm + mi * 16 + lrow) * 32 + lquad * 8]);
#pragma unroll
        for (int ni = 0; ni < 4; ni++)
            bf[ni] = *(const bf16x8*)(&Bs[(wn + ni * 16 + lrow) * 32 + lquad * 8]);
#pragma unroll
        for (int mi = 0; mi < 4; mi++)
#pragma unroll
            for (int ni = 0; ni < 4; ni++)
                acc[mi][ni] = __builtin_amdgcn_mfma_f32_16x16x32_bf16(af[mi], bf[ni], acc[mi][ni], 0, 0, 0);
    }

#pragma unroll
    for (int mi = 0; mi < 4; mi++)
#pragma unroll
        for (int r = 0; r < 4; r++) {
            int slot = m0 + wm + mi * 16 + lquad * 4 + r;
            int tok = token_list[slot];
            float w = w_list[slot];
            float* orow = out + (size_t)tok * H_DIM + n0 + wn + lrow;
#pragma unroll
            for (int ni = 0; ni < 4; ni++)
                atomicAdd(&orow[ni * 16], w * acc[mi][ni][r]);
        }
}

// ---------------- launch -----------------------------------------------------
extern "C" void kernel_launch(void* const* d_in, const int* in_sizes, int n_in,
                              void* d_out, int out_size, void* d_ws, size_t ws_size,
                              hipStream_t stream) {
    (void)in_sizes; (void)n_in;
    const float* x        = (const float*)d_in[0];
    const float* router_w = (const float*)d_in[1];
    const float* gate_w   = (const float*)d_in[2];
    const float* up_w     = (const float*)d_in[3];
    const float* down_w   = (const float*)d_in[4];
    float* out = (float*)d_out;

    const size_t W_ELEMS = (size_t)E_NUM * F_DIM * H_DIM;   // 33,554,432

    char* ws = (char*)d_ws;
    size_t off = 0;
    unsigned short* xb  = (unsigned short*)(ws + off); off += (size_t)T_TOKENS * H_DIM * 2;
    unsigned short* hid = (unsigned short*)(ws + off); off += (size_t)NSLOT_CAP * F_DIM * 2;
    int*   topk_id = (int*)(ws + off);   off += T_TOKENS * 2 * 4;
    float* topk_w  = (float*)(ws + off); off += T_TOKENS * 2 * 4;
    char* zbase = ws + off;
    int*   token_list = (int*)(ws + off);   off += NSLOT_CAP * 4;
    float* w_list     = (float*)(ws + off); off += NSLOT_CAP * 4;
    int* counts = (int*)(ws + off); off += 32;
    int* offs   = (int*)(ws + off); off += 64;
    int* fill   = (int*)(ws + off); off += 32;
    int* tile_expert = (int*)(ws + off); off += 576;
    int* tile_row    = (int*)(ws + off); off += 576;
    size_t zend = off;
    // bf16 weight buffers (new path only); dwb reuses gwb after gateup is done
    off = (off + 255) & ~(size_t)255;
    unsigned short* gwb = (unsigned short*)(ws + off); off += W_ELEMS * 2;
    unsigned short* uwb = (unsigned short*)(ws + off); off += W_ELEMS * 2;
    unsigned short* dwb = gwb;
    bool big_ws = (off <= ws_size);
    if (zend > ws_size) return;

    hipMemsetAsync(zbase, 0, (size_t)((ws + zend) - zbase), stream);
    hipMemsetAsync(d_out, 0, (size_t)out_size * 4, stream);

    cvt_x_kernel  <<<(T_TOKENS * H_DIM / 4) / 256, 256, 0, stream>>>(x, xb);
    router_kernel <<<T_TOKENS / 4, 256, 0, stream>>>(x, router_w, topk_id, topk_w, counts);
    plan_kernel   <<<1, 1, 0, stream>>>(counts, offs, tile_expert, tile_row);
    scatter_kernel<<<(T_TOKENS * 2) / 256, 256, 0, stream>>>(topk_id, topk_w, offs, fill, token_list, w_list);

    if (big_ws) {
        int wblocks = (int)(W_ELEMS / 4 / 256);
        cvt_w_kernel<<<wblocks, 256, 0, stream>>>(gate_w, gwb);
        cvt_w_kernel<<<wblocks, 256, 0, stream>>>(up_w, uwb);
        gateup_bf16_kernel<<<dim3(F_DIM / 64, MAX_TILES), 256, 0, stream>>>(
            xb, gwb, uwb, token_list, tile_expert, tile_row, hid);
        cvt_w_kernel<<<wblocks, 256, 0, stream>>>(down_w, dwb);   // reuses gwb region
        down_bf16_kernel<<<dim3(H_DIM / 128, MAX_TILES), 256, 0, stream>>>(
            hid, dwb, token_list, w_list, tile_expert, tile_row, out);
    } else {
        gateup_kernel<<<dim3(F_DIM / 128, MAX_TILES), 256, 0, stream>>>(
            xb, gate_w, up_w, token_list, tile_expert, tile_row, hid);
        down_kernel<<<dim3(H_DIM / 128, MAX_TILES), 256, 0, stream>>>(
            hid, down_w, token_list, w_list, tile_expert, tile_row, out);
    }
}